// Round 10
// baseline (560.451 us; speedup 1.0000x reference)
//
#include <hip/hip_runtime.h>
#include <cstdint>
#include <cstddef>

#define NN   4096
#define LLC  50

__device__ __forceinline__ float bf2f(unsigned short u) {
    return __uint_as_float(((unsigned)u) << 16);
}
__device__ __forceinline__ unsigned short f2bf(float x) {
    unsigned b = __float_as_uint(x);
    return (unsigned short)((b + 0x7fffu + ((b >> 16) & 1u)) >> 16);
}

#if __has_builtin(__builtin_amdgcn_sdot4)
#define SDOT4(a, b, c) __builtin_amdgcn_sdot4((int)(a), (int)(b), (c), false)
#else
__device__ __forceinline__ int sdot4_sw(unsigned a, unsigned b, int c) {
    c += (int)(signed char)(a) * (int)(signed char)(b);
    c += (int)(signed char)(a >> 8) * (int)(signed char)(b >> 8);
    c += (int)(signed char)(a >> 16) * (int)(signed char)(b >> 16);
    c += (int)(signed char)(a >> 24) * (int)(signed char)(b >> 24);
    return c;
}
#define SDOT4(a, b, c) sdot4_sw((a), (b), (c))
#endif

// sum across 64 lanes via DPP (VALU pipe); total lands in lane 63
#define DPPADD(v, ctrl, rmask) \
    ((v) + __builtin_amdgcn_update_dpp(0, (v), (ctrl), (rmask), 0xf, true))
__device__ __forceinline__ int wred64(int v) {
    v = DPPADD(v, 0x111, 0xf);   // row_shr:1
    v = DPPADD(v, 0x112, 0xf);   // row_shr:2
    v = DPPADD(v, 0x114, 0xf);   // row_shr:4
    v = DPPADD(v, 0x118, 0xf);   // row_shr:8
    v = DPPADD(v, 0x142, 0xa);   // row_bcast15
    v = DPPADD(v, 0x143, 0xc);   // row_bcast31 -> lane63=total
    return v;
}

// ---- PREP: barrier-free block-range fusion of independent work --------------
//   blk   0..15 : FULL CSR build per s — LDS histogram -> LDS prefix scan ->
//                 scatter with LDS cursor (atomicAdd in LDS, NOT fabric).
//                 The 1M device-scope cursor RMWs of the old k_scatter are
//                 gone; the whole pipeline now has zero global atomics.
//   blk  16..143: xproj (round-7-verified 25-row body)
//   blk 144..655: filt  (round-8-verified 32-row body)
// NO inter-block barriers (round-7 lesson). Block 0 additionally zeroes bar
// (replaces the memset; plain stores flushed at kernel end, and k_mega only
// touches bar with agent-scope coherence-point ops).
__global__ __launch_bounds__(256) void k_prep(
        const int* __restrict__ i0, const int* __restrict__ i1,
        const int* __restrict__ i2, const int* __restrict__ i3,
        const float* __restrict__ v0, const float* __restrict__ v1,
        const float* __restrict__ v2, const float* __restrict__ v3,
        const float* __restrict__ dd1, const float* __restrict__ dd2,
        const float* __restrict__ fea,
        const float* __restrict__ W1, const float* __restrict__ W2,
        const float* __restrict__ item_emb, const int* __restrict__ joblst,
        const float* __restrict__ W_ih,
        const float* __restrict__ b_ih, const float* __restrict__ b_hh,
        int* __restrict__ rowptr, unsigned* __restrict__ ep,
        unsigned short* __restrict__ filt1, unsigned short* __restrict__ filt2,
        float* __restrict__ xp, int* __restrict__ bar) {
    __shared__ float smem[4096];               // 16KB: CSR lc / xproj sx / filt stage
    __shared__ int wt4[4];
    int t = threadIdx.x;
    int lane = t & 63, wv = t >> 6;
    int blk = blockIdx.x;

    if (blk < 16) {
        // ---------------- CSR build, one block per s ------------------------
        int s = blk;
        int* lc = (int*)smem;
        if (blk == 0) { bar[t] = 0; bar[t + 256] = 0; }   // replaces memset
#pragma unroll
        for (int i = 0; i < 16; ++i) lc[t + i * 256] = 0;
        __syncthreads();
        unsigned m = (unsigned)s >> 2, b = (unsigned)s & 3;
        const int* ip = (m == 0) ? i0 : (m == 1) ? i1 : (m == 2) ? i2 : i3;
        const float* vp = (m == 0) ? v0 : (m == 1) ? v1 : (m == 2) ? v2 : v3;
        const int4* r4p = (const int4*)(ip + (size_t)b * 131072);
        const int4* c4p = (const int4*)(ip + (size_t)b * 131072 + 65536);
        const float4* v4p = (const float4*)(vp + (size_t)b * 65536);
        // pass 1: histogram (LDS atomics)
#pragma unroll 4
        for (int i = 0; i < 64; ++i) {
            int4 r4 = r4p[i * 256 + t];
            atomicAdd(&lc[r4.x], 1);
            atomicAdd(&lc[r4.y], 1);
            atomicAdd(&lc[r4.z], 1);
            atomicAdd(&lc[r4.w], 1);
        }
        __syncthreads();
        // prefix scan (k_scan body); write rowptr AND seed LDS cursor in-place
        int loc[16];
        int base = t * 16;
        int run = 0;
#pragma unroll
        for (int i = 0; i < 16; ++i) { loc[i] = run; run += lc[base + i]; }
        int total = run;
        int v = total;
#pragma unroll
        for (int d = 1; d < 64; d <<= 1) { int u = __shfl_up(v, d, 64); if (lane >= d) v += u; }
        if (lane == 63) wt4[wv] = v;
        __syncthreads();
        int pre = v - total;
        for (int i = 0; i < wv; ++i) pre += wt4[i];
        int* rp = rowptr + s * 4097;
#pragma unroll
        for (int i = 0; i < 16; ++i) {
            int off = pre + loc[i];
            rp[base + i] = off;
            lc[base + i] = off;                // LDS cursor (own range: no race)
        }
        if (t == 255) rp[4096] = pre + total;
        __syncthreads();
        // pass 2: scatter with LDS cursor (per-edge value math == old k_scatter)
        unsigned* eps = ep + (size_t)s * 65536;
#define SCAT1(RR, CC, VV) {                                                    \
            float vvv = (VV);                                                  \
            if (m == 1) vvv *= dd1[CC];                                        \
            if (m == 3) vvv *= dd2[CC];                                        \
            int pos = atomicAdd(&lc[RR], 1);                                   \
            eps[pos] = ((unsigned)(CC) << 16) | (unsigned)f2bf(vvv); }
#pragma unroll 4
        for (int i = 0; i < 64; ++i) {
            int4 r4 = r4p[i * 256 + t];
            int4 c4 = c4p[i * 256 + t];
            float4 vv = v4p[i * 256 + t];
            SCAT1(r4.x, c4.x, vv.x)
            SCAT1(r4.y, c4.y, vv.y)
            SCAT1(r4.z, c4.z, vv.z)
            SCAT1(r4.w, c4.w, vv.w)
        }
#undef SCAT1
    } else if (blk < 144) {
        // ---------------- xproj (round-7-verified body) ---------------------
        int wx = blk - 16;
        int nb = wx & 15, pb = wx >> 4;        // pb 0..7
        int p0 = pb * 25;
        for (int idx = t; idx < 25 * 128; idx += 256) {
            int rr = idx >> 7, c = idx & 127;
            int p = p0 + rr;
            int b = p & 3, l = p >> 2;
            int j = joblst[b * LLC + l];
            smem[idx] = item_emb[(size_t)j * 128 + c];
        }
        __syncthreads();
        int n = nb * 256 + t;
        float acc[25];
#pragma unroll
        for (int r = 0; r < 25; ++r) acc[r] = 0.f;
        const float* wn = W_ih + (size_t)n * 128;
        for (int c = 0; c < 128; c += 4) {
            float4 wq = *(const float4*)(wn + c);
#pragma unroll
            for (int r = 0; r < 25; ++r) {
                float4 xr = *(const float4*)&smem[r * 128 + c];
                acc[r] += xr.x * wq.x + xr.y * wq.y + xr.z * wq.z + xr.w * wq.w;
            }
        }
        float bias = b_ih[n] + b_hh[n];
#pragma unroll
        for (int r = 0; r < 25; ++r) xp[(size_t)(p0 + r) * NN + n] = acc[r] + bias;
    } else {
        // ---------------- filt (round-8-verified 32-row body) ---------------
        int rb = (blk - 144) * 32;
#pragma unroll
        for (int i = 0; i < 16; ++i) {
            int idx = t + i * 256;
            smem[idx] = fea[(size_t)rb * 128 + idx];
        }
        __syncthreads();
        int half = t >> 7, tc = t & 127;
        const float* sf = smem + half * 2048;  // 16 rows x 128
        float a1[16], a2[16];
#pragma unroll
        for (int r = 0; r < 16; ++r) { a1[r] = 0.f; a2[r] = 0.f; }
        for (int c = 0; c < 128; c += 4) {
            float w10 = W1[(c + 0) * 128 + tc], w11 = W1[(c + 1) * 128 + tc];
            float w12 = W1[(c + 2) * 128 + tc], w13 = W1[(c + 3) * 128 + tc];
            float w20 = W2[(c + 0) * 128 + tc], w21 = W2[(c + 1) * 128 + tc];
            float w22 = W2[(c + 2) * 128 + tc], w23 = W2[(c + 3) * 128 + tc];
#pragma unroll
            for (int r = 0; r < 16; ++r) {
                float4 f = *(const float4*)&sf[r * 128 + c];
                a1[r] += f.x * w10 + f.y * w11 + f.z * w12 + f.w * w13;
                a2[r] += f.x * w20 + f.y * w21 + f.z * w22 + f.w * w23;
            }
        }
#pragma unroll
        for (int r = 0; r < 16; ++r) {
            size_t o = (size_t)(rb + half * 16 + r) * 128 + tc;
            filt1[o] = f2bf(a1[r]);
            filt2[o] = f2bf(a2[r]);
        }
    }
}

// ---- gather edge accumulation: 2 features/lane, 8-deep pipelined, plain
// (L1/L2-cached) loads. FP accumulation order is strictly edge-sequential.
__device__ __forceinline__ void row_acc(const unsigned* __restrict__ eps, int e0, int e1,
                                        const unsigned* __restrict__ Xd, unsigned bbase,
                                        unsigned lane, float& a0, float& a1) {
    int e = e0;
    for (; e + 8 <= e1; e += 8) {
        unsigned p[8], x[8];
#pragma unroll
        for (int i = 0; i < 8; ++i) p[i] = eps[e + i];
#pragma unroll
        for (int i = 0; i < 8; ++i)
            x[i] = Xd[((size_t)(bbase + (p[i] >> 16)) << 6) + lane];
#pragma unroll
        for (int i = 0; i < 8; ++i) {
            float v = bf2f((unsigned short)p[i]);
            a0 += v * bf2f((unsigned short)x[i]);
            a1 += v * bf2f((unsigned short)(x[i] >> 16));
        }
    }
    for (; e < e1; ++e) {
        unsigned pp = eps[e];
        unsigned xw = Xd[((size_t)(bbase + (pp >> 16)) << 6) + lane];
        float v = bf2f((unsigned short)pp);
        a0 += v * bf2f((unsigned short)xw);
        a1 += v * bf2f((unsigned short)(xw >> 16));
    }
}

// ---- MEGA: RNN (blocks 0..255) || sparse gathers (blocks 256..767) ----------
// ROUND-9 EXACT (proven 300us): workers gather1 / fence-barrier / gather2+g1 /
// release+arrive(352); RNN steps 0..48 round-2-exact; step 49 fuses k_out.
__global__ __launch_bounds__(256, 2) void k_mega(
        const float* __restrict__ W_hh,
        const float* __restrict__ xp,
        unsigned* __restrict__ hq,           // [2][4096]
        int* __restrict__ bar,               // [512] ints (zeroed by k_prep)
        const int* __restrict__ rowptr,
        const unsigned* __restrict__ ep,
        const unsigned short* __restrict__ filt1,
        const unsigned short* __restrict__ filt2,
        unsigned short* __restrict__ y1,
        unsigned short* __restrict__ y2,
        const float* __restrict__ dW,
        const float* __restrict__ db,
        float* __restrict__ g1,
        float* __restrict__ out) {
    __shared__ unsigned hs[4352];              // RNN h / worker row-stage
    __shared__ int red[4][16];
    __shared__ unsigned char hpk[4][4][4];     // [wv][b][rr]
    int t = threadIdx.x;
    int lane = t & 63, wv = t >> 6;
    int blk = blockIdx.x;

    if (blk >= 256) {
        // ================== WORKER PATH: gather1 then gather2+dot ============
        int w = blk - 256;                     // 0..511; blk%8 == w%8 (XCD heuristic)
        int c7 = w & 7;
        // ---- phase 1: y = inv@filt; combo (mm,b) pinned per XCD residue ----
        {
            unsigned mm = c7 & 1, b = (unsigned)c7 >> 1;
            int s = (mm ? 8 : 0) + (int)b;
            const unsigned* Xd = (const unsigned*)(mm ? filt2 : filt1);
            unsigned* Yd = (unsigned*)(mm ? y2 : y1);
            const int* rp = rowptr + s * 4097;
            const unsigned* eps = ep + (size_t)s * 65536;
            unsigned bbase = b * 4096;
            int g = w >> 3;                    // 0..63
            int row0 = (g * 4 + wv) * 16;
            for (int rr = 0; rr < 16; ++rr) {
                int row = row0 + rr;
                float a0 = 0.f, a1 = 0.f;
                row_acc(eps, rp[row], rp[row + 1], Xd, bbase, lane, a0, a1);
                Yd[((size_t)(bbase + row) << 6) + lane] =
                    (unsigned)f2bf(a0) | ((unsigned)f2bf(a1) << 16);
            }
        }
        // ---- worker phase barrier with cross-XCD fences (per-block) ----
        __syncthreads();                       // vmcnt(0): y stores are in L2
        if (t == 0) {
            __builtin_amdgcn_fence(__ATOMIC_RELEASE, "agent");   // wbl2 -> L3
            __hip_atomic_fetch_add(&bar[320], 1, __ATOMIC_RELAXED,
                                   __HIP_MEMORY_SCOPE_AGENT);
            while (__hip_atomic_load(&bar[320], __ATOMIC_RELAXED,
                                     __HIP_MEMORY_SCOPE_AGENT) < 512)
                __builtin_amdgcn_s_sleep(4);
            __builtin_amdgcn_fence(__ATOMIC_ACQUIRE, "agent");   // inv stale L1/L2
        }
        __syncthreads();
        // ---- phase 2: rows of phi1@y1 + phi2@y2 -> gelu(row.dW[k]+db[k]) ----
        {
            unsigned b = (unsigned)c7 >> 1;
            unsigned bbase = b * 4096;
            const int* rpA = rowptr + (4 + (int)b) * 4097;
            const int* rpB = rowptr + (12 + (int)b) * 4097;
            const unsigned* epA = ep + (size_t)(4 + b) * 65536;
            const unsigned* epB = ep + (size_t)(12 + b) * 65536;
            const unsigned* y1d = (const unsigned*)y1;
            const unsigned* y2d = (const unsigned*)y2;
            int g2 = (w >> 3) * 2 + (w & 1);   // 0..127
            int row0 = (g2 * 4 + wv) * 8;
            float* fs = (float*)hs + wv * 1056;        // 8 rows x 132 (padded)
            for (int rr = 0; rr < 8; ++rr) {
                int row = row0 + rr;
                float a0 = 0.f, a1 = 0.f;
                row_acc(epA, rpA[row], rpA[row + 1], y1d, bbase, lane, a0, a1);
                row_acc(epB, rpB[row], rpB[row + 1], y2d, bbase, lane, a0, a1);
                *(float2*)(fs + rr * 132 + 2 * lane) = make_float2(a0, a1);
            }
#pragma unroll
            for (int pass = 0; pass < 2; ++pass) {
                int task = lane + pass * 64;
                if (task < 80) {
                    int rr = task / 10, k = task - rr * 10;
                    const float* rrp = fs + rr * 132;
                    const float4* wk4 = (const float4*)(dW + (size_t)k * 128);
                    float acc = 0.f;
#pragma unroll
                    for (int c4 = 0; c4 < 32; ++c4) {
                        float4 a = *(const float4*)(rrp + c4 * 4);
                        float4 wq = wk4[c4];
                        acc += a.x * wq.x + a.y * wq.y + a.z * wq.z + a.w * wq.w;
                    }
                    float pre = acc + db[k];
                    float gg = 0.5f * pre * (1.f + erff(pre * 0.70710678118f));
                    g1[(size_t)(bbase + row0 + rr) * 10 + k] = gg;
                }
            }
        }
        // ---- signal g1 complete (release -> arrive; no spin) ----
        __syncthreads();                       // drain g1 stores to L2
        if (t == 0) {
            __builtin_amdgcn_fence(__ATOMIC_RELEASE, "agent");   // wbl2: g1 -> L3
            __hip_atomic_fetch_add(&bar[352], 1, __ATOMIC_RELAXED,
                                   __HIP_MEMORY_SCOPE_AGENT);
        }
        return;
    }

    // ========================== RNN PATH (blocks 0..255) =====================
    // (byte-identical to round 2's RNN path for steps 0..48)
    int row_base = ((blk & 7) * 32 + (blk >> 3)) * 16;   // XCD-sliced: 512 rows/XCD
    int wrow = row_base + wv * 4;

    uint4 W[4][4];
    {
        const float* wsrc = W_hh + (size_t)wrow * 4096;
#pragma unroll
        for (int r = 0; r < 4; ++r)
#pragma unroll
            for (int k4 = 0; k4 < 4; ++k4) {
                unsigned q[4];
#pragma unroll
                for (int i = 0; i < 4; ++i) {
                    const float* p = wsrc + (size_t)r * 4096 + (lane * 16 + k4 * 4 + i) * 4;
                    float4 w = *(const float4*)p;
                    int q0 = (int)rintf(fminf(fmaxf(w.x * 8192.f, -127.f), 127.f));
                    int q1 = (int)rintf(fminf(fmaxf(w.y * 8192.f, -127.f), 127.f));
                    int q2 = (int)rintf(fminf(fmaxf(w.z * 8192.f, -127.f), 127.f));
                    int q3 = (int)rintf(fminf(fmaxf(w.w * 8192.f, -127.f), 127.f));
                    q[i] = (q0 & 0xff) | ((q1 & 0xff) << 8) | ((q2 & 0xff) << 16) | ((q3 & 0xff) << 24);
                }
                W[r][k4] = make_uint4(q[0], q[1], q[2], q[3]);
            }
    }

    const float SC = 1.f / (8192.f * 127.f);

    for (int l = 0; l < LLC; ++l) {
        if (l > 0) {
            const unsigned* src = hq + (size_t)((l - 1) & 1) * 4096;
            unsigned sval[16];
#pragma unroll
            for (int k = 0; k < 16; ++k)
                sval[k] = __hip_atomic_load(src + t + k * 256, __ATOMIC_RELAXED,
                                            __HIP_MEMORY_SCOPE_AGENT);
#pragma unroll
            for (int k = 0; k < 16; ++k) hs[t + k * 256] = sval[k];
            __syncthreads();

            __builtin_amdgcn_s_setprio(1);
            uint4 H[4][4];
#pragma unroll
            for (int b = 0; b < 4; ++b)
#pragma unroll
                for (int k4 = 0; k4 < 4; ++k4)
                    H[b][k4] = ((const uint4*)hs)[k4 * 256 + b * 64 + lane];
            int acc[4][4];
#pragma unroll
            for (int r = 0; r < 4; ++r)
#pragma unroll
                for (int b = 0; b < 4; ++b) acc[r][b] = 0;
#pragma unroll
            for (int k4 = 0; k4 < 4; ++k4)
#pragma unroll
                for (int r = 0; r < 4; ++r)
#pragma unroll
                    for (int b = 0; b < 4; ++b) {
                        acc[r][b] = SDOT4(W[r][k4].x, H[b][k4].x, acc[r][b]);
                        acc[r][b] = SDOT4(W[r][k4].y, H[b][k4].y, acc[r][b]);
                        acc[r][b] = SDOT4(W[r][k4].z, H[b][k4].z, acc[r][b]);
                        acc[r][b] = SDOT4(W[r][k4].w, H[b][k4].w, acc[r][b]);
                    }
#pragma unroll
            for (int r = 0; r < 4; ++r)
#pragma unroll
                for (int b = 0; b < 4; ++b) acc[r][b] = wred64(acc[r][b]);
            if (lane == 63) {
#pragma unroll
                for (int b = 0; b < 4; ++b) {
                    int4 q = { acc[0][b], acc[1][b], acc[2][b], acc[3][b] };
                    *(int4*)&red[wv][b * 4] = q;
                }
            }
            __builtin_amdgcn_s_setprio(0);
        }
        // tail: 16 lanes/wave produce 4 rows x 4 batches (same-wave LDS dep)
        float hnew = 0.f;
        if (lane < 16) {
            int b = lane >> 2, rr = lane & 3;
            int row = wrow + rr;
            float a = (l > 0) ? (float)red[wv][lane] * SC : 0.f;
            float pre = a + xp[(size_t)(l * 4 + b) * NN + row];
            hnew = tanhf(pre);
            int q = (int)rintf(hnew * 127.f);
            hpk[wv][b][rr] = (unsigned char)(q & 0xff);
        }
        if (l < LLC - 1) {
            if (lane < 4) {
                int b = lane;
                unsigned d = *(const unsigned*)&hpk[wv][b][0];
                int hk = (row_base >> 2) + wv;
                int phys = ((hk >> 2) & 3) * 1024 + b * 256 + (hk >> 4) * 4 + (hk & 3);
                __hip_atomic_store(hq + (size_t)(l & 1) * 4096 + phys, d,
                                   __ATOMIC_RELAXED, __HIP_MEMORY_SCOPE_AGENT);
            }
            // ---- all-relaxed grid barrier (round-2 exact form) ----
            __syncthreads();                   // s_waitcnt vmcnt(0): h at coherence pt
            if (t == 0) {
                int g = blk & 7;
                int old = __hip_atomic_fetch_add(&bar[g * 32], 1, __ATOMIC_RELAXED,
                                                 __HIP_MEMORY_SCOPE_AGENT);
                if ((old & 31) == 31)
                    __hip_atomic_fetch_add(&bar[256], 1, __ATOMIC_RELAXED,
                                           __HIP_MEMORY_SCOPE_AGENT);
                int target = 8 * (l + 1);
                while (__hip_atomic_load(&bar[256], __ATOMIC_RELAXED,
                                         __HIP_MEMORY_SCOPE_AGENT) < target)
                    __builtin_amdgcn_s_sleep(2);
            }
            __syncthreads();
        } else {
            // ---- final step: fused k_out (g1 ready long ago; instant poll) ----
            if (t == 0) {
                while (__hip_atomic_load(&bar[352], __ATOMIC_RELAXED,
                                         __HIP_MEMORY_SCOPE_AGENT) < 512)
                    __builtin_amdgcn_s_sleep(2);
            }
            __syncthreads();
            if (lane < 16) {
                int b = lane >> 2, rr = lane & 3;
                int row = wrow + rr;
                float ge = 0.5f * hnew * (1.f + erff(hnew * 0.70710678118f));
                size_t gb = ((size_t)b * NN + row) * 10;
#pragma unroll
                for (int k = 0; k < 10; ++k) {
                    float gv = __hip_atomic_load(g1 + gb + k, __ATOMIC_RELAXED,
                                                 __HIP_MEMORY_SCOPE_AGENT);
                    out[gb + k] = 1.f / (1.f + __expf(-gv * ge));
                }
            }
        }
    }
}

extern "C" void kernel_launch(void* const* d_in, const int* in_sizes, int n_in,
                              void* d_out, int out_size, void* d_ws, size_t ws_size,
                              hipStream_t stream) {
    const int*   phi1_idx = (const int*)d_in[0];
    const float* phi1_val = (const float*)d_in[1];
    const int*   inv1_idx = (const int*)d_in[2];
    const float* inv1_val = (const float*)d_in[3];
    const int*   phi2_idx = (const int*)d_in[4];
    const float* phi2_val = (const float*)d_in[5];
    const int*   inv2_idx = (const int*)d_in[6];
    const float* inv2_val = (const float*)d_in[7];
    const float* fea      = (const float*)d_in[8];
    const int*   joblst   = (const int*)d_in[9];
    const float* W1       = (const float*)d_in[10];
    const float* d1       = (const float*)d_in[11];
    const float* W2       = (const float*)d_in[12];
    const float* d2       = (const float*)d_in[13];
    const float* W_ih     = (const float*)d_in[14];
    const float* W_hh     = (const float*)d_in[15];
    const float* b_ih     = (const float*)d_in[16];
    const float* b_hh     = (const float*)d_in[17];
    const float* dense_W  = (const float*)d_in[18];
    const float* dense_b  = (const float*)d_in[19];
    const float* item_emb = (const float*)d_in[20];

    float* ws = (float*)d_ws;                       // slot = 4B
    unsigned short* filt1 = (unsigned short*)ws;            // 1,048,576 slots
    unsigned short* filt2 = (unsigned short*)(ws + 1048576);
    unsigned short* y1    = (unsigned short*)(ws + 2097152);
    unsigned short* y2    = (unsigned short*)(ws + 3145728);
    float* g1   = ws + 4194304;                     // 163,840 slots
    float* xp   = ws + 6291456;                     // 819,200
    unsigned* hq  = (unsigned*)(ws + 7127040);      // 8,192 (2 x 4096 dwords)
    int*   rowptr = (int*)(ws + 11395072);          // 65,552
    unsigned* ep  = (unsigned*)(ws + 11526160);     // 1,048,576 (packed col|val)
    int*   bar    = (int*)(ws + 12574736);          // 512 ints (all barrier counters)

    // Fused prep: CSR build (hist+scan+LDS-cursor scatter, zero fabric
    // atomics) | xproj | filt; also zeroes bar (replaces memset).
    k_prep<<<656, 256, 0, stream>>>(inv1_idx, phi1_idx, inv2_idx, phi2_idx,
                                    inv1_val, phi1_val, inv2_val, phi2_val,
                                    d1, d2, fea, W1, W2, item_emb, joblst,
                                    W_ih, b_ih, b_hh,
                                    rowptr, ep, filt1, filt2, xp, bar);

    // RNN (0..255) || workers (256..767); final RNN step emits out directly.
    k_mega<<<768, 256, 0, stream>>>(W_hh, xp, hq, bar,
                                    rowptr, ep, filt1, filt2, y1, y2,
                                    dense_W, dense_b, g1, (float*)d_out);
}